// Round 17
// baseline (164.272 us; speedup 1.0000x reference)
//
#include <hip/hip_runtime.h>
#include <math.h>

// Sizes (fixed by the reference)
#define Zc   4
#define Nc   128
#define EMBc 16
#define L0c  32
#define MLPHc 64
#define GEOc 64
#define NBc  32
#define NHc  128
#define Cc   128   // MLPH + GEO
#define SLc  64    // split-K slices (K-slice 256), all layers

typedef float  f32x4  __attribute__((ext_vector_type(4)));
typedef short  bf16x8 __attribute__((ext_vector_type(8)));

union FragU {
    bf16x8 v;
    unsigned short u[8];
    uint2 q2[2];
};

struct P {
    const float *geom, *mask, *emb;
    const int*   features;
    const float *pw0,*pb0,*w1a,*b1a,*w1b,*b1b,*w2a,*b2a,*w2b,*b2b;
    const float *r00,*r01,*r02, *r10,*r11,*r12, *r20,*r21,*r22;
    const float *e1w,*e1b,*bn1g,*bn1b,*e2w,*e2b,*bn2g,*bn2b;
    unsigned short *h2buf, *gt, *packs;
    float *part, *f0, *geo_pn, *outp;
};

__device__ __forceinline__ float sp5(float x){
    float y = 5.0f * x;
    float t = fabsf(y);
    return (fmaxf(y, 0.0f) + log1pf(__expf(-t))) * 0.2f;
}
// post-accumulator activation: input y = 5*preact (5 folded into weights)
__device__ __forceinline__ float ssp5_post(float y){
    float e = __expf(-fabsf(y));
    float u = fmaxf(y, 0.0f) + __logf(1.0f + e);
    return fmaf(0.2f, u, -0.13862943611198906f);
}
__device__ __forceinline__ unsigned int cvtpk_bf16(float a, float b){
    unsigned int r;
    asm("v_cvt_pk_bf16_f32 %0, %1, %2" : "=v"(r) : "v"(a), "v"(b));
    return r;
}
__device__ __forceinline__ unsigned short f2bf(float f){
    unsigned int u = __float_as_uint(f);
    unsigned int r = (u + 0x7FFFu + ((u >> 16) & 1u)) >> 16;
    return (unsigned short)r;
}
__device__ __forceinline__ int kmap(int l, int e){
    return 4*((l >> 4) & 3) + (e & 3) + 16*(e >> 2);
}

// ---------------------------------------------------------------------------
// init: blocks 0..127 pointnet (4 atoms each); 128..367 packw; 368 zero d_out.
__device__ void init_dev(int bx, const P& p, char* smem)
{
    float* cur = (float*)smem;            // 4*64
    float* tmp = cur + 4*GEOc;            // 4*64
    int t = threadIdx.x;
    if (bx < 128){
        int g  = t >> 6;
        int c  = t & 63;
        int zn = bx*4 + g;
        float gx = p.geom[zn*3+0], gy = p.geom[zn*3+1], gz = p.geom[zn*3+2];
        float v = fmaf(gx, p.pw0[0*GEOc+c], fmaf(gy, p.pw0[1*GEOc+c],
                  fmaf(gz, p.pw0[2*GEOc+c], p.pb0[c])));
        const float* WA[2] = {p.w1a, p.w2a}; const float* BA[2] = {p.b1a, p.b2a};
        const float* WB[2] = {p.w1b, p.w2b}; const float* BB[2] = {p.b1b, p.b2b};
        #pragma unroll
        for (int blk = 0; blk < 2; blk++){
            cur[g*GEOc + c] = v;
            __syncthreads();
            float s = BA[blk][c];
            for (int k = 0; k < GEOc; k++)
                s = fmaf(fmaxf(cur[g*GEOc + k], 0.0f), WA[blk][k*GEOc+c], s);
            tmp[g*GEOc + c] = s;
            __syncthreads();
            float s2 = BB[blk][c];
            for (int k = 0; k < GEOc; k++)
                s2 = fmaf(fmaxf(tmp[g*GEOc + k], 0.0f), WB[blk][k*GEOc+c], s2);
            v = v + s2;
            __syncthreads();
        }
        p.geo_pn[zn*GEOc + c] = v * p.mask[zn];
        if (c < EMBc){
            int fi = p.features[zn];
            p.f0[zn*EMBc + c] = p.emb[fi*EMBc + c] * p.mask[zn] * 0.0022038655607334227f;
        }
    } else if (bx < 368){
        int j = bx - 128;
        int layer = j / 80;
        int sub = j % 80;
        const float* w0s = (layer == 0) ? p.r00 : (layer == 1) ? p.r10 : p.r20;
        const float* w1s = (layer == 0) ? p.r01 : (layer == 1) ? p.r11 : p.r21;
        unsigned short* p0 = p.packs + layer*4096;
        unsigned short* p1 = p.packs + 12288 + layer*16384;
        int idx = sub*256 + t;
        if (idx < 4096){
            int t8 = idx >> 9, l = (idx >> 3) & 63, e = idx & 7;
            int k = kmap(l, e);
            int n = (t8 << 4) + (l & 15);
            p0[idx] = f2bf(w0s[k*NHc + n] * 0.8838834764831844f);   // 5/sqrt(32)
        } else {
            int jj = idx - 4096;
            int fid = jj >> 9, l = (jj >> 3) & 63, e = jj & 7;
            int kk = fid >> 3, t8 = fid & 7;
            int k = 32*kk + kmap(l, e);
            int n = 16*t8 + (l & 15);
            p1[jj] = f2bf(w1s[k*NHc + n] * 0.4419417382415922f);    // 5/sqrt(128)
        }
    } else {
        for (int i = t; i < Zc*2*Cc; i += 256) p.outp[i] = 0.0f;
    }
}

// ---------------------------------------------------------------------------
// pair-MLP, ONE WAVE per unit (64 thr, 4 KB LDS), 3 LAYERS looped per unit
// (basis A-frag is layer-independent: computed once).  Dense upper-triangle
// enumeration -> no idle launched waves.  h2 [z][a][b][n] upper-tri stores.
__device__ void pairmlp_dev(int z, int a, int bc, const P& p, char* smem)
{
    char* lb = smem;                        // 4 KB swizzled h1 tile (16 rows)
    int l   = threadIdx.x;                  // 0..63
    int g16 = l >> 4;
    int c   = l & 15;

    int bp = bc + c;
    float ax = p.geom[(z*Nc + a)*3 + 0];
    float ay = p.geom[(z*Nc + a)*3 + 1];
    float az = p.geom[(z*Nc + a)*3 + 2];
    float dx = p.geom[(z*Nc + bp)*3 + 0] - ax;
    float dy = p.geom[(z*Nc + bp)*3 + 1] - ay;
    float dz = p.geom[(z*Nc + bp)*3 + 2] - az;
    float rm = sqrtf(dx*dx + dy*dy + dz*dz);

    // basis A-fragment: SAME for all 3 layers (depends only on rm)
    FragU af;
    #pragma unroll
    for (int e = 0; e < 8; e++){
        int k = kmap(l, e);
        float x = fmaf(rm, 3.1f, -(float)k);
        float v = 0.0f;
        if (fabsf(x) < 1.0f){ float cc = __cosf(1.57079632679f*x); v = cc*cc; }
        af.u[e] = (unsigned short)cvtpk_bf16(v, v);
    }

    size_t zbase = (size_t)z*Nc*Nc*NHc;
    int mrow = c;
    int sw   = (mrow & 7) << 4;

    for (int layer = 0; layer < 3; layer++){
        const unsigned short* wp0 = p.packs + layer*4096;
        const unsigned short* wp1 = p.packs + 12288 + layer*16384;
        unsigned short* h2 = p.h2buf + (size_t)layer * ((size_t)Zc*Nc*Nc*NHc);

        // phase 1: h1 = ssp(basis @ w0pack)
        f32x4 acc[8];
        #pragma unroll
        for (int t8 = 0; t8 < 8; t8++) acc[t8] = (f32x4){0.f,0.f,0.f,0.f};
        #pragma unroll
        for (int t8 = 0; t8 < 8; t8++){
            bf16x8 bf = *reinterpret_cast<const bf16x8*>(wp0 + ((t8*64 + l) << 3));
            acc[t8] = __builtin_amdgcn_mfma_f32_16x16x32_bf16(af.v, bf, acc[t8], 0, 0, 0);
        }
        #pragma unroll
        for (int t8 = 0; t8 < 8; t8++){
            #pragma unroll
            for (int rg = 0; rg < 4; rg++){
                int m = 4*g16 + rg;               // pair row 0..15
                int n = 16*t8 + c;
                int off = ((m << 8) + (n << 1)) ^ ((m & 7) << 4);
                *(unsigned short*)(lb + off) = (unsigned short)cvtpk_bf16(ssp5_post(acc[t8][rg]), 0.0f);
            }
        }
        __syncthreads();   // single wave: orders LDS writes before reads

        // phase 2: h2 = ssp(h1 @ w1pack)
        f32x4 acc2[8];
        #pragma unroll
        for (int t8 = 0; t8 < 8; t8++) acc2[t8] = (f32x4){0.f,0.f,0.f,0.f};
        #pragma unroll
        for (int kk = 0; kk < 4; kk++){
            int ob = (mrow << 8) + (kk << 6) + (g16 << 3);
            FragU a2;
            a2.q2[0] = *(const uint2*)(lb + (ob ^ sw));
            a2.q2[1] = *(const uint2*)(lb + ((ob + 32) ^ sw));
            #pragma unroll
            for (int t8 = 0; t8 < 8; t8++){
                bf16x8 bf = *reinterpret_cast<const bf16x8*>(wp1 + (((kk*8 + t8)*64 + l) << 3));
                acc2[t8] = __builtin_amdgcn_mfma_f32_16x16x32_bf16(a2.v, bf, acc2[t8], 0, 0, 0);
            }
        }
        #pragma unroll
        for (int t8 = 0; t8 < 8; t8++){
            #pragma unroll
            for (int rg = 0; rg < 4; rg++){
                int m = 4*g16 + rg;
                int b = bc + m;
                unsigned short val = (unsigned short)cvtpk_bf16(ssp5_post(acc2[t8][rg]), 0.0f);
                h2[zbase + ((size_t)a*Nc + b)*NHc + 16*t8 + c] = val;
            }
        }
        __syncthreads();   // lb reuse across layers (same wave; cheap)
    }
}

// ---------------------------------------------------------------------------
// gt producer, 64-thread variant (layer 0 only): vb in [0,4096).
// gt[z][i][b*NH+m], lane-coalesced (m fastest).
__device__ void gmat64_dev(int vb, const float* f, const float* w2,
                           unsigned short* gt, char* smem)
{
    float (*fsh)[EMBc] = (float (*)[EMBc])smem;     // 8 x 16 floats = 512 B
    int t  = threadIdx.x;                            // 0..63
    int gbx = vb >> 6;                               // 0..63  -> zb0
    int msub = vb & 63;                              // 0..63  -> mi block
    int zb0 = gbx * 8;
    {
        int idx = t;
        #pragma unroll
        for (int q = 0; q < 2; q++, idx += 64){
            int r = idx >> 4, j = idx & 15;
            fsh[r][j] = f[(zb0 + r)*EMBc + j];
        }
    }
    __syncthreads();
    int mi = msub*64 + t;                            // 0..4095
    int m_ = mi & (NHc-1);
    int i_ = mi >> 7;
    const float* wrow = w2 + (size_t)(m_*L0c + i_) * EMBc;
    float s[8];
    #pragma unroll
    for (int r = 0; r < 8; r++) s[r] = 0.0f;
    #pragma unroll
    for (int j4 = 0; j4 < EMBc/4; j4++){
        float4 wv4 = *reinterpret_cast<const float4*>(&wrow[j4*4]);
        #pragma unroll
        for (int q = 0; q < 4; q++){
            float wv = reinterpret_cast<const float*>(&wv4)[q];
            int j = j4*4 + q;
            #pragma unroll
            for (int r = 0; r < 8; r++)
                s[r] = fmaf(fsh[r][j], wv, s[r]);
        }
    }
    int z = zb0 >> 7;
    #pragma unroll
    for (int r = 0; r < 8; r++){
        int b = (zb0 + r) & (Nc-1);
        gt[((size_t)z*L0c + i_)*(Nc*NHc) + b*NHc + m_] = (unsigned short)cvtpk_bf16(s[r], s[r]);
    }
}

// ---------------------------------------------------------------------------
// Fused previous-layer epilogue + gt producer (256 thr, part sum over SLc).
template<int DIN, int DOUT>
__device__ void egmat_dev(int vb, const float* part, const float* mask,
                          const float* w2, unsigned short* gt, char* smem)
{
    float (*fsh)[DIN] = (float (*)[DIN])smem;
    int t  = threadIdx.x;
    int bx = vb & 63, by = vb >> 6;
    int zb0 = bx * 8;
    for (int idx = t; idx < 8*DIN; idx += 256){
        int r = idx / DIN, j = idx % DIN;
        int zb = zb0 + r;
        float s = 0.0f;
        #pragma unroll
        for (int sl = 0; sl < SLc; sl++)
            s += part[(size_t)sl*(Zc*Nc*DIN) + zb*DIN + j];
        float m = mask[zb];
        fsh[r][j] = sp5(s) * m * m * 0.0022038655607334227f;
    }
    __syncthreads();
    int mi = by * 256 + t;
    int m_ = mi & (NHc-1);
    int i_ = mi >> 7;
    const float* wrow = w2 + (size_t)(m_*DOUT + i_) * DIN;
    float s[8];
    #pragma unroll
    for (int r = 0; r < 8; r++) s[r] = 0.0f;
    #pragma unroll
    for (int j4 = 0; j4 < DIN/4; j4++){
        float4 wv4 = *reinterpret_cast<const float4*>(&wrow[j4*4]);
        #pragma unroll
        for (int q = 0; q < 4; q++){
            float wv = reinterpret_cast<const float*>(&wv4)[q];
            int j = j4*4 + q;
            #pragma unroll
            for (int r = 0; r < 8; r++)
                s[r] = fmaf(fsh[r][j], wv, s[r]);
        }
    }
    int z = zb0 >> 7;
    #pragma unroll
    for (int r = 0; r < 8; r++){
        int b = (zb0 + r) & (Nc-1);
        gt[((size_t)z*DOUT + i_)*(Nc*NHc) + b*NHc + m_] = (unsigned short)cvtpk_bf16(s[r], s[r]);
    }
}

// ---------------------------------------------------------------------------
// MFMA contraction: partial[s][z][a][i] = sum_{k' in slice} h2[z,a,k']*gt[z,i,k']
// h2 stored upper-triangle only: A-stage reads h2[a][b] if b>=a else h2[b][a].
template<int DOUT, int KS>
__device__ void gemm3_dev(int vb, const unsigned short* h2, const unsigned short* gt,
                          float* partial, char* smem)
{
    constexpr int NS   = (Nc*NHc)/KS;
    constexpr int ROWB = KS*2;
    unsigned short* Ash = (unsigned short*)smem;
    unsigned short* Bsh = (unsigned short*)(smem + 64*ROWB);
    int t = threadIdx.x;
    int w = t >> 6, l = t & 63;
    int g16 = l >> 4, c16 = l & 15;
    int s  = vb % NS;
    int at = (vb / NS) & 1;
    int z  = vb / (NS*2);
    int a0 = at*64;
    int k0 = s*KS;

    {
        constexpr int ITA = (64*(KS/8))/256;
        #pragma unroll
        for (int it = 0; it < ITA; it++){
            int idx = it*256 + t;
            int r = idx / (KS/8), c8 = idx % (KS/8);
            int aRow = a0 + r;
            int kk = k0 + c8*8;
            int b  = kk >> 7;              // NHc = 128
            int m8 = kk & (NHc-1);
            const unsigned short* srcp = (b >= aRow)
                ? h2 + ((size_t)(z*Nc + aRow))*(Nc*NHc) + b*NHc + m8
                : h2 + ((size_t)(z*Nc + b))*(Nc*NHc) + aRow*NHc + m8;
            uint4 v = *reinterpret_cast<const uint4*>(srcp);
            int byte = (r*ROWB + c8*16) ^ ((r & 7) << 4);
            *reinterpret_cast<uint4*>((char*)Ash + byte) = v;
        }
    }
    {
        const unsigned short* src = gt + ((size_t)z*DOUT)*(Nc*NHc) + k0;
        constexpr int ITB = (DOUT*(KS/8))/256;
        #pragma unroll
        for (int it = 0; it < ITB; it++){
            int idx = it*256 + t;
            int r = idx / (KS/8), c8 = idx % (KS/8);
            uint4 v = *reinterpret_cast<const uint4*>(src + (size_t)r*(Nc*NHc) + c8*8);
            int byte = (r*ROWB + c8*16) ^ ((r & 7) << 4);
            *reinterpret_cast<uint4*>((char*)Bsh + byte) = v;
        }
    }
    __syncthreads();

    constexpr int NT = DOUT/16;
    f32x4 acc[NT];
    #pragma unroll
    for (int nt = 0; nt < NT; nt++) acc[nt] = (f32x4){0.f,0.f,0.f,0.f};
    int ar  = 16*w + c16;
    int asw = (ar & 7) << 4;
    #pragma unroll
    for (int ks = 0; ks < KS/32; ks++){
        FragU afr;
        int abyte = ar*ROWB + ks*64 + g16*8;
        afr.q2[0] = *(const uint2*)((char*)Ash + (abyte ^ asw));
        afr.q2[1] = *(const uint2*)((char*)Ash + ((abyte + 32) ^ asw));
        #pragma unroll
        for (int nt = 0; nt < NT; nt++){
            int br  = nt*16 + c16;
            int bsw = (br & 7) << 4;
            int bbyte = br*ROWB + ks*64 + g16*8;
            FragU bfr;
            bfr.q2[0] = *(const uint2*)((char*)Bsh + (bbyte ^ bsw));
            bfr.q2[1] = *(const uint2*)((char*)Bsh + ((bbyte + 32) ^ bsw));
            acc[nt] = __builtin_amdgcn_mfma_f32_16x16x32_bf16(afr.v, bfr.v, acc[nt], 0, 0, 0);
        }
    }
    #pragma unroll
    for (int nt = 0; nt < NT; nt++){
        #pragma unroll
        for (int rg = 0; rg < 4; rg++){
            int a = a0 + 16*w + 4*g16 + rg;
            int i = nt*16 + c16;
            partial[(((size_t)s*Zc + z)*Nc + a)*DOUT + i] = acc[nt][rg];
        }
    }
}

// ---------------------------------------------------------------------------
// Tail: layer-2 epilogue -> x1 -> bn1+leaky -> x2 -> bn2+leaky -> masked
// atomic sum into d_out.  Needs 4128 B of LDS.
__device__ void tail_dev(int n, const P& p, char* smem)
{
    float* feat = (float*)smem;          // [Zc][Cc] = 2048 B
    float* xln  = feat + Zc*Cc;          // [Zc][Cc] = 2048 B
    float* r1   = xln + Zc*Cc;           // 16 B
    float* r2   = r1 + 4;                // 16 B
    int t = threadIdx.x;

    {
        int z = t >> 6, i = t & 63;
        float s = 0.0f;
        #pragma unroll
        for (int sl = 0; sl < SLc; sl++)
            s += p.part[((size_t)sl*Zc*Nc + z*Nc + n)*MLPHc + i];
        float m = p.mask[z*Nc + n];
        feat[z*Cc + i] = sp5(s) * m;
        feat[z*Cc + MLPHc + i] = p.geo_pn[(z*Nc + n)*GEOc + i];
    }
    __syncthreads();

    int c  = t & 127;
    int zh = t >> 7;
    float x1v[2];
    float sum = 0.0f, sq = 0.0f;
    #pragma unroll
    for (int q = 0; q < 2; q++){
        int z = zh*2 + q;
        float s = p.e1b[c];
        for (int k = 0; k < Cc; k++) s = fmaf(feat[z*Cc + k], p.e1w[k*Cc + c], s);
        x1v[q] = s; sum += s; sq = fmaf(s, s, sq);
    }
    #pragma unroll
    for (int off = 32; off > 0; off >>= 1){
        sum += __shfl_down(sum, off);
        sq  += __shfl_down(sq,  off);
    }
    if ((t & 63) == 0){ r1[t >> 6] = sum; r2[t >> 6] = sq; }
    __syncthreads();
    {
        float tot  = r1[0]+r1[1]+r1[2]+r1[3];
        float totq = r2[0]+r2[1]+r2[2]+r2[3];
        float mu   = tot * (1.0f/512.0f);
        float var  = totq * (1.0f/512.0f) - mu*mu;
        float rstd = rsqrtf(var + 1e-5f);
        float ga = p.bn1g[n], be = p.bn1b[n];
        #pragma unroll
        for (int q = 0; q < 2; q++){
            float v = (x1v[q] - mu) * rstd * ga + be;
            xln[(zh*2 + q)*Cc + c] = v > 0.0f ? v : 0.2f*v;
        }
    }
    __syncthreads();

    float x2v[4];
    sum = 0.0f; sq = 0.0f;
    #pragma unroll
    for (int z = 0; z < Zc; z++){
        float s = p.e2b[t];
        for (int k = 0; k < Cc; k++) s = fmaf(xln[z*Cc + k], p.e2w[k*2*Cc + t], s);
        x2v[z] = s; sum += s; sq = fmaf(s, s, sq);
    }
    #pragma unroll
    for (int off = 32; off > 0; off >>= 1){
        sum += __shfl_down(sum, off);
        sq  += __shfl_down(sq,  off);
    }
    if ((t & 63) == 0){ r1[t >> 6] = sum; r2[t >> 6] = sq; }
    __syncthreads();
    {
        float tot  = r1[0]+r1[1]+r1[2]+r1[3];
        float totq = r2[0]+r2[1]+r2[2]+r2[3];
        float mu   = tot * (1.0f/1024.0f);
        float var  = totq * (1.0f/1024.0f) - mu*mu;
        float rstd = rsqrtf(var + 1e-5f);
        float ga = p.bn2g[n], be = p.bn2b[n];
        #pragma unroll
        for (int z = 0; z < Zc; z++){
            float v = (x2v[z] - mu) * rstd * ga + be;
            v = v > 0.0f ? v : 0.2f*v;
            atomicAdd(&p.outp[z*2*Cc + t], v * p.mask[z*Nc + n]);
        }
    }
}

// ---------------------------------------------------------------------------
// Kernels.
__global__ __launch_bounds__(256) void k_init_g(P p){
    __shared__ __align__(16) char smem[2048];
    init_dev(blockIdx.x, p, smem);
}
// 64-thread blocks: [0,2304) dense pairmlp wave-units (3 layers looped);
// [2304,6400) gmat L0.  Dense enumeration per z: u in [0,576); chunk k:
// 8k(k+1)<=u<8(k+1)(k+2), a = u-8k(k+1) (< 16(k+1) -> wave has work), bc=16k.
__global__ __launch_bounds__(64) void k_pm(P p){
    __shared__ __align__(16) char smem[4096];
    int bx = blockIdx.x;
    if (bx < 2304){
        int z = bx / 576;
        int u = bx - z*576;
        int k = (int)((sqrtf(2.0f*(float)u + 4.0f) - 2.0f) * 0.25f);
        while (8*(k+1)*(k+2) <= u) ++k;
        while (k > 0 && 8*k*(k+1) > u) --k;
        int a  = u - 8*k*(k+1);
        int bc = 16*k;
        pairmlp_dev(z, a, bc, p, smem);
    } else {
        gmat64_dev(bx - 2304, p.f0, p.r02, p.gt, smem);
    }
}
template<int DIN, int DOUT>
__global__ __launch_bounds__(256) void k_egmat_g(P p, const float* w2){
    __shared__ __align__(16) char smem[8*DIN*4];
    egmat_dev<DIN,DOUT>(blockIdx.y*64 + blockIdx.x, p.part, p.mask, w2, p.gt, smem);
}
template<int DOUT, int KS>
__global__ __launch_bounds__(256) void k_gemm3_g(P p, const unsigned short* h2){
    __shared__ __align__(16) char smem[(64+DOUT)*KS*2];
    constexpr int NS = (Nc*NHc)/KS;
    int vb = (blockIdx.z*2 + blockIdx.y)*NS + blockIdx.x;
    gemm3_dev<DOUT,KS>(vb, h2, p.gt, p.part, smem);
}
__global__ __launch_bounds__(256) void k_tail_g(P p){
    __shared__ __align__(16) char smem[4224];   // tail_dev needs 4128 B
    tail_dev(blockIdx.x, p, smem);
}

// ---------------------------------------------------------------------------
extern "C" void kernel_launch(void* const* d_in, const int* in_sizes, int n_in,
                              void* d_out, int out_size, void* d_ws, size_t ws_size,
                              hipStream_t stream)
{
    P p;
    p.features = (const int*)  d_in[0];
    p.geom     = (const float*)d_in[1];
    p.mask     = (const float*)d_in[2];
    p.emb      = (const float*)d_in[3];
    p.r00 = (const float*)d_in[4];  p.r01 = (const float*)d_in[5];  p.r02 = (const float*)d_in[6];
    p.r10 = (const float*)d_in[7];  p.r11 = (const float*)d_in[8];  p.r12 = (const float*)d_in[9];
    p.r20 = (const float*)d_in[10]; p.r21 = (const float*)d_in[11]; p.r22 = (const float*)d_in[12];
    p.pw0 = (const float*)d_in[13]; p.pb0 = (const float*)d_in[14];
    p.w1a = (const float*)d_in[15]; p.b1a = (const float*)d_in[16];
    p.w1b = (const float*)d_in[17]; p.b1b = (const float*)d_in[18];
    p.w2a = (const float*)d_in[19]; p.b2a = (const float*)d_in[20];
    p.w2b = (const float*)d_in[21]; p.b2b = (const float*)d_in[22];
    p.e1w = (const float*)d_in[23]; p.e1b = (const float*)d_in[24];
    p.bn1g= (const float*)d_in[25]; p.bn1b= (const float*)d_in[26];
    p.e2w = (const float*)d_in[27]; p.e2b = (const float*)d_in[28];
    p.bn2g= (const float*)d_in[29]; p.bn2b= (const float*)d_in[30];

    float* ws = (float*)d_ws;
    p.h2buf = (unsigned short*)ws;                         // 3 * 8,388,608 ushort
    p.gt    = (unsigned short*)(ws + 12582912);            // 4,194,304 ushort
    p.part  = ws + 12582912 + 2097152;                     // 64 slices * Z*N*64
    p.f0    = p.part + 2097152;                            // Z*N*EMB
    p.geo_pn= p.f0 + 8192;                                 // Z*N*64
    p.packs = (unsigned short*)(p.geo_pn + 32768);         // 61440 ushorts
    p.outp  = (float*)d_out;
    (void)ws_size; (void)in_sizes; (void)n_in; (void)out_size;

    const size_t H2L = (size_t)Zc*Nc*Nc*NHc;

    k_init_g<<<369, 256, 0, stream>>>(p);
    // pairmlp (dense upper-tri wave units, 3 layers looped) + gmat layer-0
    k_pm<<<6400, 64, 0, stream>>>(p);
    // layer 0
    k_gemm3_g<32,256><<<dim3(64, 2, Zc), 256, 0, stream>>>(p, p.h2buf);
    // layer 1
    k_egmat_g<32,32><<<dim3(64, 16), 256, 0, stream>>>(p, p.r12);
    k_gemm3_g<32,256><<<dim3(64, 2, Zc), 256, 0, stream>>>(p, p.h2buf + H2L);
    // layer 2
    k_egmat_g<32,64><<<dim3(64, 32), 256, 0, stream>>>(p, p.r22);
    k_gemm3_g<64,256><<<dim3(64, 2, Zc), 256, 0, stream>>>(p, p.h2buf + 2*H2L);
    // fused tail
    k_tail_g<<<128, 256, 0, stream>>>(p);
}

// Round 18
// 145.998 us; speedup vs baseline: 1.1252x; 1.1252x over previous
//
#include <hip/hip_runtime.h>
#include <math.h>

// Sizes (fixed by the reference)
#define Zc   4
#define Nc   128
#define EMBc 16
#define L0c  32
#define MLPHc 64
#define GEOc 64
#define NBc  32
#define NHc  128
#define Cc   128   // MLPH + GEO
#define SLc  64    // split-K slices (K-slice 256), all layers

typedef float  f32x4  __attribute__((ext_vector_type(4)));
typedef short  bf16x8 __attribute__((ext_vector_type(8)));

union FragU {
    bf16x8 v;
    unsigned short u[8];
    uint2 q2[2];
};

struct P {
    const float *geom, *mask, *emb;
    const int*   features;
    const float *pw0,*pb0,*w1a,*b1a,*w1b,*b1b,*w2a,*b2a,*w2b,*b2b;
    const float *r00,*r01,*r02, *r10,*r11,*r12, *r20,*r21,*r22;
    const float *e1w,*e1b,*bn1g,*bn1b,*e2w,*e2b,*bn2g,*bn2b;
    unsigned short *h2buf, *gt, *packs;
    float *part, *f0, *geo_pn, *outp;
};

__device__ __forceinline__ float sp5(float x){
    float y = 5.0f * x;
    float t = fabsf(y);
    return (fmaxf(y, 0.0f) + log1pf(__expf(-t))) * 0.2f;
}
// post-accumulator activation: input y = 5*preact (5 folded into weights)
__device__ __forceinline__ float ssp5_post(float y){
    float e = __expf(-fabsf(y));
    float u = fmaxf(y, 0.0f) + __logf(1.0f + e);
    return fmaf(0.2f, u, -0.13862943611198906f);
}
__device__ __forceinline__ unsigned int cvtpk_bf16(float a, float b){
    unsigned int r;
    asm("v_cvt_pk_bf16_f32 %0, %1, %2" : "=v"(r) : "v"(a), "v"(b));
    return r;
}
__device__ __forceinline__ unsigned short f2bf(float f){
    unsigned int u = __float_as_uint(f);
    unsigned int r = (u + 0x7FFFu + ((u >> 16) & 1u)) >> 16;
    return (unsigned short)r;
}
__device__ __forceinline__ int kmap(int l, int e){
    return 4*((l >> 4) & 3) + (e & 3) + 16*(e >> 2);
}

// ---------------------------------------------------------------------------
// init: blocks 0..127 pointnet (4 atoms each); 128..367 packw; 368 zero d_out.
__device__ void init_dev(int bx, const P& p, char* smem)
{
    float* cur = (float*)smem;            // 4*64
    float* tmp = cur + 4*GEOc;            // 4*64
    int t = threadIdx.x;
    if (bx < 128){
        int g  = t >> 6;
        int c  = t & 63;
        int zn = bx*4 + g;
        float gx = p.geom[zn*3+0], gy = p.geom[zn*3+1], gz = p.geom[zn*3+2];
        float v = fmaf(gx, p.pw0[0*GEOc+c], fmaf(gy, p.pw0[1*GEOc+c],
                  fmaf(gz, p.pw0[2*GEOc+c], p.pb0[c])));
        const float* WA[2] = {p.w1a, p.w2a}; const float* BA[2] = {p.b1a, p.b2a};
        const float* WB[2] = {p.w1b, p.w2b}; const float* BB[2] = {p.b1b, p.b2b};
        #pragma unroll
        for (int blk = 0; blk < 2; blk++){
            cur[g*GEOc + c] = v;
            __syncthreads();
            float s = BA[blk][c];
            for (int k = 0; k < GEOc; k++)
                s = fmaf(fmaxf(cur[g*GEOc + k], 0.0f), WA[blk][k*GEOc+c], s);
            tmp[g*GEOc + c] = s;
            __syncthreads();
            float s2 = BB[blk][c];
            for (int k = 0; k < GEOc; k++)
                s2 = fmaf(fmaxf(tmp[g*GEOc + k], 0.0f), WB[blk][k*GEOc+c], s2);
            v = v + s2;
            __syncthreads();
        }
        p.geo_pn[zn*GEOc + c] = v * p.mask[zn];
        if (c < EMBc){
            int fi = p.features[zn];
            p.f0[zn*EMBc + c] = p.emb[fi*EMBc + c] * p.mask[zn] * 0.0022038655607334227f;
        }
    } else if (bx < 368){
        int j = bx - 128;
        int layer = j / 80;
        int sub = j % 80;
        const float* w0s = (layer == 0) ? p.r00 : (layer == 1) ? p.r10 : p.r20;
        const float* w1s = (layer == 0) ? p.r01 : (layer == 1) ? p.r11 : p.r21;
        unsigned short* p0 = p.packs + layer*4096;
        unsigned short* p1 = p.packs + 12288 + layer*16384;
        int idx = sub*256 + t;
        if (idx < 4096){
            int t8 = idx >> 9, l = (idx >> 3) & 63, e = idx & 7;
            int k = kmap(l, e);
            int n = (t8 << 4) + (l & 15);
            p0[idx] = f2bf(w0s[k*NHc + n] * 0.8838834764831844f);   // 5/sqrt(32)
        } else {
            int jj = idx - 4096;
            int fid = jj >> 9, l = (jj >> 3) & 63, e = jj & 7;
            int kk = fid >> 3, t8 = fid & 7;
            int k = 32*kk + kmap(l, e);
            int n = 16*t8 + (l & 15);
            p1[jj] = f2bf(w1s[k*NHc + n] * 0.4419417382415922f);    // 5/sqrt(128)
        }
    } else {
        for (int i = t; i < Zc*2*Cc; i += 256) p.outp[i] = 0.0f;
    }
}

// ---------------------------------------------------------------------------
// pair-MLP, ONE WAVE per unit (64 thr, 4 KB LDS): dense upper-triangle
// enumeration -> no idle launched waves, LDS-limited occupancy 16 waves/CU.
// Unit = (layer, z, a, b-chunk bc..bc+15).  h2 [z][a][b][n] upper-tri stores.
// (r17 lesson: do NOT loop layers per wave — latency-bound phase needs TLP.)
__device__ void pairmlp_dev(int layer, int z, int a, int bc, const P& p, char* smem)
{
    char* lb = smem;                        // 4 KB swizzled h1 tile (16 rows)
    int l   = threadIdx.x;                  // 0..63
    int g16 = l >> 4;
    int c   = l & 15;

    const unsigned short* wp0 = p.packs + layer*4096;
    const unsigned short* wp1 = p.packs + 12288 + layer*16384;
    unsigned short* h2 = p.h2buf + (size_t)layer * ((size_t)Zc*Nc*Nc*NHc);

    int bp = bc + c;
    float ax = p.geom[(z*Nc + a)*3 + 0];
    float ay = p.geom[(z*Nc + a)*3 + 1];
    float az = p.geom[(z*Nc + a)*3 + 2];
    float dx = p.geom[(z*Nc + bp)*3 + 0] - ax;
    float dy = p.geom[(z*Nc + bp)*3 + 1] - ay;
    float dz = p.geom[(z*Nc + bp)*3 + 2] - az;
    float rm = sqrtf(dx*dx + dy*dy + dz*dz);

    FragU af;
    #pragma unroll
    for (int e = 0; e < 8; e++){
        int k = kmap(l, e);
        float x = fmaf(rm, 3.1f, -(float)k);
        float v = 0.0f;
        if (fabsf(x) < 1.0f){ float cc = __cosf(1.57079632679f*x); v = cc*cc; }
        af.u[e] = (unsigned short)cvtpk_bf16(v, v);
    }

    // phase 1: h1 = ssp(basis @ w0pack)
    f32x4 acc[8];
    #pragma unroll
    for (int t8 = 0; t8 < 8; t8++) acc[t8] = (f32x4){0.f,0.f,0.f,0.f};
    #pragma unroll
    for (int t8 = 0; t8 < 8; t8++){
        bf16x8 bf = *reinterpret_cast<const bf16x8*>(wp0 + ((t8*64 + l) << 3));
        acc[t8] = __builtin_amdgcn_mfma_f32_16x16x32_bf16(af.v, bf, acc[t8], 0, 0, 0);
    }
    #pragma unroll
    for (int t8 = 0; t8 < 8; t8++){
        #pragma unroll
        for (int rg = 0; rg < 4; rg++){
            int m = 4*g16 + rg;               // pair row 0..15
            int n = 16*t8 + c;
            int off = ((m << 8) + (n << 1)) ^ ((m & 7) << 4);
            *(unsigned short*)(lb + off) = (unsigned short)cvtpk_bf16(ssp5_post(acc[t8][rg]), 0.0f);
        }
    }
    __syncthreads();   // single wave: just orders LDS writes before reads

    // phase 2: h2 = ssp(h1 @ w1pack)
    f32x4 acc2[8];
    #pragma unroll
    for (int t8 = 0; t8 < 8; t8++) acc2[t8] = (f32x4){0.f,0.f,0.f,0.f};
    int mrow = c;
    int sw   = (mrow & 7) << 4;
    #pragma unroll
    for (int kk = 0; kk < 4; kk++){
        int ob = (mrow << 8) + (kk << 6) + (g16 << 3);
        FragU a2;
        a2.q2[0] = *(const uint2*)(lb + (ob ^ sw));
        a2.q2[1] = *(const uint2*)(lb + ((ob + 32) ^ sw));
        #pragma unroll
        for (int t8 = 0; t8 < 8; t8++){
            bf16x8 bf = *reinterpret_cast<const bf16x8*>(wp1 + (((kk*8 + t8)*64 + l) << 3));
            acc2[t8] = __builtin_amdgcn_mfma_f32_16x16x32_bf16(a2.v, bf, acc2[t8], 0, 0, 0);
        }
    }
    size_t zbase = (size_t)z*Nc*Nc*NHc;
    #pragma unroll
    for (int t8 = 0; t8 < 8; t8++){
        #pragma unroll
        for (int rg = 0; rg < 4; rg++){
            int m = 4*g16 + rg;
            int b = bc + m;
            unsigned short val = (unsigned short)cvtpk_bf16(ssp5_post(acc2[t8][rg]), 0.0f);
            h2[zbase + ((size_t)a*Nc + b)*NHc + 16*t8 + c] = val;
        }
    }
}

// ---------------------------------------------------------------------------
// gt producer, 64-thread variant (layer 0 only): vb in [0,4096).
// gt[z][i][b*NH+m], lane-coalesced (m fastest).
__device__ void gmat64_dev(int vb, const float* f, const float* w2,
                           unsigned short* gt, char* smem)
{
    float (*fsh)[EMBc] = (float (*)[EMBc])smem;     // 8 x 16 floats = 512 B
    int t  = threadIdx.x;                            // 0..63
    int gbx = vb >> 6;                               // 0..63  -> zb0
    int msub = vb & 63;                              // 0..63  -> mi block
    int zb0 = gbx * 8;
    {
        int idx = t;
        #pragma unroll
        for (int q = 0; q < 2; q++, idx += 64){
            int r = idx >> 4, j = idx & 15;
            fsh[r][j] = f[(zb0 + r)*EMBc + j];
        }
    }
    __syncthreads();
    int mi = msub*64 + t;                            // 0..4095
    int m_ = mi & (NHc-1);
    int i_ = mi >> 7;
    const float* wrow = w2 + (size_t)(m_*L0c + i_) * EMBc;
    float s[8];
    #pragma unroll
    for (int r = 0; r < 8; r++) s[r] = 0.0f;
    #pragma unroll
    for (int j4 = 0; j4 < EMBc/4; j4++){
        float4 wv4 = *reinterpret_cast<const float4*>(&wrow[j4*4]);
        #pragma unroll
        for (int q = 0; q < 4; q++){
            float wv = reinterpret_cast<const float*>(&wv4)[q];
            int j = j4*4 + q;
            #pragma unroll
            for (int r = 0; r < 8; r++)
                s[r] = fmaf(fsh[r][j], wv, s[r]);
        }
    }
    int z = zb0 >> 7;
    #pragma unroll
    for (int r = 0; r < 8; r++){
        int b = (zb0 + r) & (Nc-1);
        gt[((size_t)z*L0c + i_)*(Nc*NHc) + b*NHc + m_] = (unsigned short)cvtpk_bf16(s[r], s[r]);
    }
}

// ---------------------------------------------------------------------------
// Fused previous-layer epilogue + gt producer (256 thr, part sum over SLc).
template<int DIN, int DOUT>
__device__ void egmat_dev(int vb, const float* part, const float* mask,
                          const float* w2, unsigned short* gt, char* smem)
{
    float (*fsh)[DIN] = (float (*)[DIN])smem;
    int t  = threadIdx.x;
    int bx = vb & 63, by = vb >> 6;
    int zb0 = bx * 8;
    for (int idx = t; idx < 8*DIN; idx += 256){
        int r = idx / DIN, j = idx % DIN;
        int zb = zb0 + r;
        float s = 0.0f;
        #pragma unroll
        for (int sl = 0; sl < SLc; sl++)
            s += part[(size_t)sl*(Zc*Nc*DIN) + zb*DIN + j];
        float m = mask[zb];
        fsh[r][j] = sp5(s) * m * m * 0.0022038655607334227f;
    }
    __syncthreads();
    int mi = by * 256 + t;
    int m_ = mi & (NHc-1);
    int i_ = mi >> 7;
    const float* wrow = w2 + (size_t)(m_*DOUT + i_) * DIN;
    float s[8];
    #pragma unroll
    for (int r = 0; r < 8; r++) s[r] = 0.0f;
    #pragma unroll
    for (int j4 = 0; j4 < DIN/4; j4++){
        float4 wv4 = *reinterpret_cast<const float4*>(&wrow[j4*4]);
        #pragma unroll
        for (int q = 0; q < 4; q++){
            float wv = reinterpret_cast<const float*>(&wv4)[q];
            int j = j4*4 + q;
            #pragma unroll
            for (int r = 0; r < 8; r++)
                s[r] = fmaf(fsh[r][j], wv, s[r]);
        }
    }
    int z = zb0 >> 7;
    #pragma unroll
    for (int r = 0; r < 8; r++){
        int b = (zb0 + r) & (Nc-1);
        gt[((size_t)z*DOUT + i_)*(Nc*NHc) + b*NHc + m_] = (unsigned short)cvtpk_bf16(s[r], s[r]);
    }
}

// ---------------------------------------------------------------------------
// MFMA contraction: partial[s][z][a][i] = sum_{k' in slice} h2[z,a,k']*gt[z,i,k']
// h2 stored upper-triangle only: A-stage reads h2[a][b] if b>=a else h2[b][a].
template<int DOUT, int KS>
__device__ void gemm3_dev(int vb, const unsigned short* h2, const unsigned short* gt,
                          float* partial, char* smem)
{
    constexpr int NS   = (Nc*NHc)/KS;
    constexpr int ROWB = KS*2;
    unsigned short* Ash = (unsigned short*)smem;
    unsigned short* Bsh = (unsigned short*)(smem + 64*ROWB);
    int t = threadIdx.x;
    int w = t >> 6, l = t & 63;
    int g16 = l >> 4, c16 = l & 15;
    int s  = vb % NS;
    int at = (vb / NS) & 1;
    int z  = vb / (NS*2);
    int a0 = at*64;
    int k0 = s*KS;

    {
        constexpr int ITA = (64*(KS/8))/256;
        #pragma unroll
        for (int it = 0; it < ITA; it++){
            int idx = it*256 + t;
            int r = idx / (KS/8), c8 = idx % (KS/8);
            int aRow = a0 + r;
            int kk = k0 + c8*8;
            int b  = kk >> 7;              // NHc = 128
            int m8 = kk & (NHc-1);
            const unsigned short* srcp = (b >= aRow)
                ? h2 + ((size_t)(z*Nc + aRow))*(Nc*NHc) + b*NHc + m8
                : h2 + ((size_t)(z*Nc + b))*(Nc*NHc) + aRow*NHc + m8;
            uint4 v = *reinterpret_cast<const uint4*>(srcp);
            int byte = (r*ROWB + c8*16) ^ ((r & 7) << 4);
            *reinterpret_cast<uint4*>((char*)Ash + byte) = v;
        }
    }
    {
        const unsigned short* src = gt + ((size_t)z*DOUT)*(Nc*NHc) + k0;
        constexpr int ITB = (DOUT*(KS/8))/256;
        #pragma unroll
        for (int it = 0; it < ITB; it++){
            int idx = it*256 + t;
            int r = idx / (KS/8), c8 = idx % (KS/8);
            uint4 v = *reinterpret_cast<const uint4*>(src + (size_t)r*(Nc*NHc) + c8*8);
            int byte = (r*ROWB + c8*16) ^ ((r & 7) << 4);
            *reinterpret_cast<uint4*>((char*)Bsh + byte) = v;
        }
    }
    __syncthreads();

    constexpr int NT = DOUT/16;
    f32x4 acc[NT];
    #pragma unroll
    for (int nt = 0; nt < NT; nt++) acc[nt] = (f32x4){0.f,0.f,0.f,0.f};
    int ar  = 16*w + c16;
    int asw = (ar & 7) << 4;
    #pragma unroll
    for (int ks = 0; ks < KS/32; ks++){
        FragU afr;
        int abyte = ar*ROWB + ks*64 + g16*8;
        afr.q2[0] = *(const uint2*)((char*)Ash + (abyte ^ asw));
        afr.q2[1] = *(const uint2*)((char*)Ash + ((abyte + 32) ^ asw));
        #pragma unroll
        for (int nt = 0; nt < NT; nt++){
            int br  = nt*16 + c16;
            int bsw = (br & 7) << 4;
            int bbyte = br*ROWB + ks*64 + g16*8;
            FragU bfr;
            bfr.q2[0] = *(const uint2*)((char*)Bsh + (bbyte ^ bsw));
            bfr.q2[1] = *(const uint2*)((char*)Bsh + ((bbyte + 32) ^ bsw));
            acc[nt] = __builtin_amdgcn_mfma_f32_16x16x32_bf16(afr.v, bfr.v, acc[nt], 0, 0, 0);
        }
    }
    #pragma unroll
    for (int nt = 0; nt < NT; nt++){
        #pragma unroll
        for (int rg = 0; rg < 4; rg++){
            int a = a0 + 16*w + 4*g16 + rg;
            int i = nt*16 + c16;
            partial[(((size_t)s*Zc + z)*Nc + a)*DOUT + i] = acc[nt][rg];
        }
    }
}

// ---------------------------------------------------------------------------
// Tail: layer-2 epilogue -> x1 -> bn1+leaky -> x2 -> bn2+leaky -> masked
// atomic sum into d_out.  Needs 4128 B of LDS.
__device__ void tail_dev(int n, const P& p, char* smem)
{
    float* feat = (float*)smem;          // [Zc][Cc] = 2048 B
    float* xln  = feat + Zc*Cc;          // [Zc][Cc] = 2048 B
    float* r1   = xln + Zc*Cc;           // 16 B
    float* r2   = r1 + 4;                // 16 B
    int t = threadIdx.x;

    {
        int z = t >> 6, i = t & 63;
        float s = 0.0f;
        #pragma unroll
        for (int sl = 0; sl < SLc; sl++)
            s += p.part[((size_t)sl*Zc*Nc + z*Nc + n)*MLPHc + i];
        float m = p.mask[z*Nc + n];
        feat[z*Cc + i] = sp5(s) * m;
        feat[z*Cc + MLPHc + i] = p.geo_pn[(z*Nc + n)*GEOc + i];
    }
    __syncthreads();

    int c  = t & 127;
    int zh = t >> 7;
    float x1v[2];
    float sum = 0.0f, sq = 0.0f;
    #pragma unroll
    for (int q = 0; q < 2; q++){
        int z = zh*2 + q;
        float s = p.e1b[c];
        for (int k = 0; k < Cc; k++) s = fmaf(feat[z*Cc + k], p.e1w[k*Cc + c], s);
        x1v[q] = s; sum += s; sq = fmaf(s, s, sq);
    }
    #pragma unroll
    for (int off = 32; off > 0; off >>= 1){
        sum += __shfl_down(sum, off);
        sq  += __shfl_down(sq,  off);
    }
    if ((t & 63) == 0){ r1[t >> 6] = sum; r2[t >> 6] = sq; }
    __syncthreads();
    {
        float tot  = r1[0]+r1[1]+r1[2]+r1[3];
        float totq = r2[0]+r2[1]+r2[2]+r2[3];
        float mu   = tot * (1.0f/512.0f);
        float var  = totq * (1.0f/512.0f) - mu*mu;
        float rstd = rsqrtf(var + 1e-5f);
        float ga = p.bn1g[n], be = p.bn1b[n];
        #pragma unroll
        for (int q = 0; q < 2; q++){
            float v = (x1v[q] - mu) * rstd * ga + be;
            xln[(zh*2 + q)*Cc + c] = v > 0.0f ? v : 0.2f*v;
        }
    }
    __syncthreads();

    float x2v[4];
    sum = 0.0f; sq = 0.0f;
    #pragma unroll
    for (int z = 0; z < Zc; z++){
        float s = p.e2b[t];
        for (int k = 0; k < Cc; k++) s = fmaf(xln[z*Cc + k], p.e2w[k*2*Cc + t], s);
        x2v[z] = s; sum += s; sq = fmaf(s, s, sq);
    }
    #pragma unroll
    for (int off = 32; off > 0; off >>= 1){
        sum += __shfl_down(sum, off);
        sq  += __shfl_down(sq,  off);
    }
    if ((t & 63) == 0){ r1[t >> 6] = sum; r2[t >> 6] = sq; }
    __syncthreads();
    {
        float tot  = r1[0]+r1[1]+r1[2]+r1[3];
        float totq = r2[0]+r2[1]+r2[2]+r2[3];
        float mu   = tot * (1.0f/1024.0f);
        float var  = totq * (1.0f/1024.0f) - mu*mu;
        float rstd = rsqrtf(var + 1e-5f);
        float ga = p.bn2g[n], be = p.bn2b[n];
        #pragma unroll
        for (int z = 0; z < Zc; z++){
            float v = (x2v[z] - mu) * rstd * ga + be;
            v = v > 0.0f ? v : 0.2f*v;
            atomicAdd(&p.outp[z*2*Cc + t], v * p.mask[z*Nc + n]);
        }
    }
}

// ---------------------------------------------------------------------------
// Kernels.
__global__ __launch_bounds__(256) void k_init_g(P p){
    __shared__ __align__(16) char smem[2048];
    init_dev(blockIdx.x, p, smem);
}
// 64-thread blocks: [0,6912) dense pairmlp wave-units; [6912,11008) gmat L0.
// Dense enumeration per (layer,z): u in [0,576); chunk k: 8k(k+1)<=u<8(k+1)(k+2),
// a = u-8k(k+1) (< 16(k+1) guarantees the wave has work), bc = 16k.
__global__ __launch_bounds__(64) void k_pm(P p){
    __shared__ __align__(16) char smem[4096];
    int bx = blockIdx.x;
    if (bx < 6912){
        int layer = bx / 2304;
        int rem   = bx - layer*2304;
        int z     = rem / 576;
        int u     = rem - z*576;
        int k = (int)((sqrtf(2.0f*(float)u + 4.0f) - 2.0f) * 0.25f);
        while (8*(k+1)*(k+2) <= u) ++k;
        while (k > 0 && 8*k*(k+1) > u) --k;
        int a  = u - 8*k*(k+1);
        int bc = 16*k;
        pairmlp_dev(layer, z, a, bc, p, smem);
    } else {
        gmat64_dev(bx - 6912, p.f0, p.r02, p.gt, smem);
    }
}
template<int DIN, int DOUT>
__global__ __launch_bounds__(256) void k_egmat_g(P p, const float* w2){
    __shared__ __align__(16) char smem[8*DIN*4];
    egmat_dev<DIN,DOUT>(blockIdx.y*64 + blockIdx.x, p.part, p.mask, w2, p.gt, smem);
}
template<int DOUT, int KS>
__global__ __launch_bounds__(256) void k_gemm3_g(P p, const unsigned short* h2){
    __shared__ __align__(16) char smem[(64+DOUT)*KS*2];
    constexpr int NS = (Nc*NHc)/KS;
    int vb = (blockIdx.z*2 + blockIdx.y)*NS + blockIdx.x;
    gemm3_dev<DOUT,KS>(vb, h2, p.gt, p.part, smem);
}
__global__ __launch_bounds__(256) void k_tail_g(P p){
    __shared__ __align__(16) char smem[4224];   // tail_dev needs 4128 B
    tail_dev(blockIdx.x, p, smem);
}

// ---------------------------------------------------------------------------
extern "C" void kernel_launch(void* const* d_in, const int* in_sizes, int n_in,
                              void* d_out, int out_size, void* d_ws, size_t ws_size,
                              hipStream_t stream)
{
    P p;
    p.features = (const int*)  d_in[0];
    p.geom     = (const float*)d_in[1];
    p.mask     = (const float*)d_in[2];
    p.emb      = (const float*)d_in[3];
    p.r00 = (const float*)d_in[4];  p.r01 = (const float*)d_in[5];  p.r02 = (const float*)d_in[6];
    p.r10 = (const float*)d_in[7];  p.r11 = (const float*)d_in[8];  p.r12 = (const float*)d_in[9];
    p.r20 = (const float*)d_in[10]; p.r21 = (const float*)d_in[11]; p.r22 = (const float*)d_in[12];
    p.pw0 = (const float*)d_in[13]; p.pb0 = (const float*)d_in[14];
    p.w1a = (const float*)d_in[15]; p.b1a = (const float*)d_in[16];
    p.w1b = (const float*)d_in[17]; p.b1b = (const float*)d_in[18];
    p.w2a = (const float*)d_in[19]; p.b2a = (const float*)d_in[20];
    p.w2b = (const float*)d_in[21]; p.b2b = (const float*)d_in[22];
    p.e1w = (const float*)d_in[23]; p.e1b = (const float*)d_in[24];
    p.bn1g= (const float*)d_in[25]; p.bn1b= (const float*)d_in[26];
    p.e2w = (const float*)d_in[27]; p.e2b = (const float*)d_in[28];
    p.bn2g= (const float*)d_in[29]; p.bn2b= (const float*)d_in[30];

    float* ws = (float*)d_ws;
    p.h2buf = (unsigned short*)ws;                         // 3 * 8,388,608 ushort
    p.gt    = (unsigned short*)(ws + 12582912);            // 4,194,304 ushort
    p.part  = ws + 12582912 + 2097152;                     // 64 slices * Z*N*64
    p.f0    = p.part + 2097152;                            // Z*N*EMB
    p.geo_pn= p.f0 + 8192;                                 // Z*N*64
    p.packs = (unsigned short*)(p.geo_pn + 32768);         // 61440 ushorts
    p.outp  = (float*)d_out;
    (void)ws_size; (void)in_sizes; (void)n_in; (void)out_size;

    const size_t H2L = (size_t)Zc*Nc*Nc*NHc;

    k_init_g<<<369, 256, 0, stream>>>(p);
    // pairmlp (dense upper-tri wave units) + gmat layer-0, 64-thr blocks
    k_pm<<<11008, 64, 0, stream>>>(p);
    // layer 0
    k_gemm3_g<32,256><<<dim3(64, 2, Zc), 256, 0, stream>>>(p, p.h2buf);
    // layer 1
    k_egmat_g<32,32><<<dim3(64, 16), 256, 0, stream>>>(p, p.r12);
    k_gemm3_g<32,256><<<dim3(64, 2, Zc), 256, 0, stream>>>(p, p.h2buf + H2L);
    // layer 2
    k_egmat_g<32,64><<<dim3(64, 32), 256, 0, stream>>>(p, p.r22);
    k_gemm3_g<64,256><<<dim3(64, 2, Zc), 256, 0, stream>>>(p, p.h2buf + 2*H2L);
    // fused tail
    k_tail_g<<<128, 256, 0, stream>>>(p);
}